// Round 4
// baseline (82.650 us; speedup 1.0000x reference)
//
#include <hip/hip_runtime.h>

// Bahdanau additive attention scores:
//   enc = keys @ W1 + b1          [B,S,U]
//   dec = query @ W2 + b2         [B,T,U]
//   score[b,t,s] = bV + sum_u tanh(enc[b,s,u] + dec[b,t,u]) * V[u]
//
// B=4, T=128, S=512, D=128, U=128. All fp32.
//
// Strategy: two kernels.
//  K1: precompute enc2/dec2 = (x@W + b) * (2/ln2) into d_ws.
//      Pre-scaling lets K2 feed v_exp_f32 (2^x) directly:
//      tanh(x) = 1 - 2 * rcp(exp2(x * 2/ln2) + 1)
//  K2: fused score. score = (bV + sum(V)) - 2 * sum_u V[u]*rcp(exp2(e2+d2)+1)
//      -> per element-u: add, exp, add, rcp, fma (3 VALU + 2 trans). Compute-bound.
//      Never materializes the [B,T,S,U] hidden tensor (134 MB in the reference).

#define B_ 4
#define T_ 128
#define S_ 512
#define D_ 128
#define U_ 128

// 2/ln(2)
#define SCALE2 2.88539008177792681f

// ---------------------------------------------------------------------------
// Kernel 1: enc2[r][u] = SCALE2*(sum_k x[r][k]*W[k][u] + bias[u])
// 2048 enc rows (keys) + 512 dec rows (query) = 2560 rows.
// Block = 256 threads handles 8 rows x 128 u; each thread: 4 rows, 1 u.
// blocks 0..255 -> enc (keys/W1/b1), blocks 256..319 -> dec (query/W2/b2).
// ---------------------------------------------------------------------------
__global__ __launch_bounds__(256) void precompute_kernel(
    const float* __restrict__ query, const float* __restrict__ keys,
    const float* __restrict__ W1, const float* __restrict__ b1,
    const float* __restrict__ W2, const float* __restrict__ b2,
    float* __restrict__ enc2, float* __restrict__ dec2)
{
    __shared__ float xs[8][132];   // 8 rows x 128 k, padded stride

    const int blk = blockIdx.x;
    const float* src;
    const float* W;
    const float* bias;
    float* dst;
    if (blk < 256) {
        int row0 = blk * 8;
        src = keys + row0 * D_;
        W = W1; bias = b1;
        dst = enc2 + row0 * U_;
    } else {
        int row0 = (blk - 256) * 8;
        src = query + row0 * D_;
        W = W2; bias = b2;
        dst = dec2 + row0 * U_;
    }

    const int tid = threadIdx.x;

    // stage 8x128 floats = 256 float4, one per thread, fully coalesced
    {
        int r = tid >> 5;          // /32 float4-per-row
        int c4 = tid & 31;
        float4 v = reinterpret_cast<const float4*>(src)[tid];
        *reinterpret_cast<float4*>(&xs[r][c4 * 4]) = v;
    }
    __syncthreads();

    const int u = tid & 127;
    const int rh = tid >> 7;       // 0/1 -> rows rh*4 .. rh*4+3
    const float bb = bias[u];

    float acc0 = 0.f, acc1 = 0.f, acc2 = 0.f, acc3 = 0.f;
    #pragma unroll 4
    for (int k4 = 0; k4 < 32; ++k4) {
        const int k = k4 * 4;
        float4 x0 = *reinterpret_cast<const float4*>(&xs[rh * 4 + 0][k]);
        float4 x1 = *reinterpret_cast<const float4*>(&xs[rh * 4 + 1][k]);
        float4 x2 = *reinterpret_cast<const float4*>(&xs[rh * 4 + 2][k]);
        float4 x3 = *reinterpret_cast<const float4*>(&xs[rh * 4 + 3][k]);
        float w0 = W[(k + 0) * U_ + u];
        float w1 = W[(k + 1) * U_ + u];
        float w2 = W[(k + 2) * U_ + u];
        float w3 = W[(k + 3) * U_ + u];
        acc0 += x0.x * w0 + x0.y * w1 + x0.z * w2 + x0.w * w3;
        acc1 += x1.x * w0 + x1.y * w1 + x1.z * w2 + x1.w * w3;
        acc2 += x2.x * w0 + x2.y * w1 + x2.z * w2 + x2.w * w3;
        acc3 += x3.x * w0 + x3.y * w1 + x3.z * w2 + x3.w * w3;
    }

    dst[(rh * 4 + 0) * U_ + u] = SCALE2 * (acc0 + bb);
    dst[(rh * 4 + 1) * U_ + u] = SCALE2 * (acc1 + bb);
    dst[(rh * 4 + 2) * U_ + u] = SCALE2 * (acc2 + bb);
    dst[(rh * 4 + 3) * U_ + u] = SCALE2 * (acc3 + bb);
}

// ---------------------------------------------------------------------------
// Kernel 2: fused score. Block = 256 threads handles a 16t x 32s tile for one b.
// Thread (tt = tid>>4, ss = tid&15) computes outputs (tt, ss) and (tt, ss+16).
// grid = (S/32, T/16, B) = (16, 8, 4) = 512 blocks.
// LDS ~26 KB/block -> 6 blocks/CU by LDS; grid gives 2 blocks/CU (8 waves).
// ---------------------------------------------------------------------------
__global__ __launch_bounds__(256) void score_kernel(
    const float* __restrict__ enc2, const float* __restrict__ dec2,
    const float* __restrict__ V, const float* __restrict__ bV,
    float* __restrict__ out)
{
    __shared__ float se[32][132];  // enc tile, padded stride (132*4B=528B, 16B-aligned rows)
    __shared__ float sd[16][132];  // dec tile
    __shared__ float sv[128];      // V
    __shared__ float sC;           // bV + sum(V)

    const int b  = blockIdx.z;
    const int t0 = blockIdx.y * 16;
    const int s0 = blockIdx.x * 32;
    const int tid = threadIdx.x;

    // stage enc tile: 32 rows x 128 floats = 1024 float4 -> 4/thread, coalesced
    {
        const float4* esrc = reinterpret_cast<const float4*>(enc2 + (b * S_ + s0) * U_);
        #pragma unroll
        for (int j = 0; j < 4; ++j) {
            int f = tid + j * 256;
            int r = f >> 5, c4 = f & 31;
            float4 v = esrc[f];
            *reinterpret_cast<float4*>(&se[r][c4 * 4]) = v;
        }
    }
    // stage dec tile: 16 rows x 128 floats = 512 float4 -> 2/thread
    {
        const float4* dsrc = reinterpret_cast<const float4*>(dec2 + (b * T_ + t0) * U_);
        #pragma unroll
        for (int j = 0; j < 2; ++j) {
            int f = tid + j * 256;
            int r = f >> 5, c4 = f & 31;
            float4 v = dsrc[f];
            *reinterpret_cast<float4*>(&sd[r][c4 * 4]) = v;
        }
    }
    // stage V (32 float4) + reduce sum(V) within lanes 0..31 of wave 0
    if (tid < 32) {
        float4 v = reinterpret_cast<const float4*>(V)[tid];
        *reinterpret_cast<float4*>(&sv[tid * 4]) = v;
        float p = v.x + v.y + v.z + v.w;
        p += __shfl_xor(p, 1);
        p += __shfl_xor(p, 2);
        p += __shfl_xor(p, 4);
        p += __shfl_xor(p, 8);
        p += __shfl_xor(p, 16);
        if (tid == 0) sC = p + bV[0];
    }
    __syncthreads();

    const int tt = tid >> 4;
    const int ss = tid & 15;
    const float* dp = &sd[tt][0];
    const float* ea = &se[ss][0];
    const float* eb = &se[ss + 16][0];

    // Split accumulators: halves the serial FMA dependency chain per output
    // (8 waves/CU may not fully hide 4-cy FMA latency on a single chain).
    float accA0 = 0.f, accA1 = 0.f, accB0 = 0.f, accB1 = 0.f;
    #pragma unroll 8
    for (int k4 = 0; k4 < 32; ++k4) {
        float4 d  = *reinterpret_cast<const float4*>(dp + k4 * 4);
        float4 a  = *reinterpret_cast<const float4*>(ea + k4 * 4);
        float4 e2 = *reinterpret_cast<const float4*>(eb + k4 * 4);
        float4 vv = *reinterpret_cast<const float4*>(&sv[k4 * 4]);
        // r = 1/(exp2(x2)+1); tanh = 1-2r folded into epilogue via sC
        accA0 += vv.x * __builtin_amdgcn_rcpf(__builtin_amdgcn_exp2f(d.x + a.x) + 1.f);
        accA1 += vv.y * __builtin_amdgcn_rcpf(__builtin_amdgcn_exp2f(d.y + a.y) + 1.f);
        accA0 += vv.z * __builtin_amdgcn_rcpf(__builtin_amdgcn_exp2f(d.z + a.z) + 1.f);
        accA1 += vv.w * __builtin_amdgcn_rcpf(__builtin_amdgcn_exp2f(d.w + a.w) + 1.f);
        accB0 += vv.x * __builtin_amdgcn_rcpf(__builtin_amdgcn_exp2f(d.x + e2.x) + 1.f);
        accB1 += vv.y * __builtin_amdgcn_rcpf(__builtin_amdgcn_exp2f(d.y + e2.y) + 1.f);
        accB0 += vv.z * __builtin_amdgcn_rcpf(__builtin_amdgcn_exp2f(d.z + e2.z) + 1.f);
        accB1 += vv.w * __builtin_amdgcn_rcpf(__builtin_amdgcn_exp2f(d.w + e2.w) + 1.f);
    }

    const float C = sC;
    const int obase = (b * T_ + t0 + tt) * S_ + s0 + ss;
    out[obase]      = C - 2.f * (accA0 + accA1);
    out[obase + 16] = C - 2.f * (accB0 + accB1);
}

// ---------------------------------------------------------------------------
extern "C" void kernel_launch(void* const* d_in, const int* in_sizes, int n_in,
                              void* d_out, int out_size, void* d_ws, size_t ws_size,
                              hipStream_t stream)
{
    const float* query = (const float*)d_in[0];
    const float* keys  = (const float*)d_in[1];
    const float* W1    = (const float*)d_in[2];
    const float* b1    = (const float*)d_in[3];
    const float* W2    = (const float*)d_in[4];
    const float* b2    = (const float*)d_in[5];
    const float* V     = (const float*)d_in[6];
    const float* bV    = (const float*)d_in[7];
    float* out = (float*)d_out;

    float* enc2 = (float*)d_ws;                    // [B*S][U] = 2048*128 floats (1 MB)
    float* dec2 = enc2 + (B_ * S_ * U_);           // [B*T][U] = 512*128 floats (256 KB)

    precompute_kernel<<<dim3(320), dim3(256), 0, stream>>>(
        query, keys, W1, b1, W2, b2, enc2, dec2);

    score_kernel<<<dim3(S_ / 32, T_ / 16, B_), dim3(256), 0, stream>>>(
        enc2, dec2, V, bV, out);
}

// Round 5
// 78.562 us; speedup vs baseline: 1.0520x; 1.0520x over previous
//
#include <hip/hip_runtime.h>

// Bahdanau additive attention scores:
//   enc = keys @ W1 + b1          [B,S,U]
//   dec = query @ W2 + b2         [B,T,U]
//   score[b,t,s] = bV + sum_u tanh(enc[b,s,u] + dec[b,t,u]) * V[u]
//
// B=4, T=128, S=512, D=128, U=128. All fp32.
//
// R5: exp-factorization. tanh(x) = 1 - 2/(exp2(x*2/ln2)+1) and
//     exp2(d+e) = exp2(d)*exp2(e), so K1 stores E=exp2(SCALE2*enc),
//     D=exp2(SCALE2*dec) and K2's inner element is just
//        acc += v * rcp(fma(E, D, 1))     (2 VALU + 1 trans, was 3+2)
//     halving the transcendental-pipe load. unroll 8 -> 4 to cap VGPR
//     pressure (spill suspicion from R4's 82.65us with invisible kernels).

#define B_ 4
#define T_ 128
#define S_ 512
#define D_ 128
#define U_ 128

// 2/ln(2)
#define SCALE2 2.88539008177792681f

// ---------------------------------------------------------------------------
// Kernel 1: encE[r][u] = exp2( SCALE2*(sum_k x[r][k]*W[k][u] + bias[u]) )
// 2048 enc rows (keys) + 512 dec rows (query) = 2560 rows.
// Block = 256 threads handles 8 rows x 128 u; each thread: 4 rows, 1 u.
// blocks 0..255 -> enc (keys/W1/b1), blocks 256..319 -> dec (query/W2/b2).
// ---------------------------------------------------------------------------
__global__ __launch_bounds__(256) void precompute_kernel(
    const float* __restrict__ query, const float* __restrict__ keys,
    const float* __restrict__ W1, const float* __restrict__ b1,
    const float* __restrict__ W2, const float* __restrict__ b2,
    float* __restrict__ encE, float* __restrict__ decE)
{
    __shared__ float xs[8][132];   // 8 rows x 128 k, padded stride

    const int blk = blockIdx.x;
    const float* src;
    const float* W;
    const float* bias;
    float* dst;
    if (blk < 256) {
        int row0 = blk * 8;
        src = keys + row0 * D_;
        W = W1; bias = b1;
        dst = encE + row0 * U_;
    } else {
        int row0 = (blk - 256) * 8;
        src = query + row0 * D_;
        W = W2; bias = b2;
        dst = decE + row0 * U_;
    }

    const int tid = threadIdx.x;

    // stage 8x128 floats = 256 float4, one per thread, fully coalesced
    {
        int r = tid >> 5;          // /32 float4-per-row
        int c4 = tid & 31;
        float4 v = reinterpret_cast<const float4*>(src)[tid];
        *reinterpret_cast<float4*>(&xs[r][c4 * 4]) = v;
    }
    __syncthreads();

    const int u = tid & 127;
    const int rh = tid >> 7;       // 0/1 -> rows rh*4 .. rh*4+3
    const float bb = bias[u];

    float acc0 = 0.f, acc1 = 0.f, acc2 = 0.f, acc3 = 0.f;
    #pragma unroll 4
    for (int k4 = 0; k4 < 32; ++k4) {
        const int k = k4 * 4;
        float4 x0 = *reinterpret_cast<const float4*>(&xs[rh * 4 + 0][k]);
        float4 x1 = *reinterpret_cast<const float4*>(&xs[rh * 4 + 1][k]);
        float4 x2 = *reinterpret_cast<const float4*>(&xs[rh * 4 + 2][k]);
        float4 x3 = *reinterpret_cast<const float4*>(&xs[rh * 4 + 3][k]);
        float w0 = W[(k + 0) * U_ + u];
        float w1 = W[(k + 1) * U_ + u];
        float w2 = W[(k + 2) * U_ + u];
        float w3 = W[(k + 3) * U_ + u];
        acc0 += x0.x * w0 + x0.y * w1 + x0.z * w2 + x0.w * w3;
        acc1 += x1.x * w0 + x1.y * w1 + x1.z * w2 + x1.w * w3;
        acc2 += x2.x * w0 + x2.y * w1 + x2.z * w2 + x2.w * w3;
        acc3 += x3.x * w0 + x3.y * w1 + x3.z * w2 + x3.w * w3;
    }

    dst[(rh * 4 + 0) * U_ + u] = __builtin_amdgcn_exp2f(SCALE2 * (acc0 + bb));
    dst[(rh * 4 + 1) * U_ + u] = __builtin_amdgcn_exp2f(SCALE2 * (acc1 + bb));
    dst[(rh * 4 + 2) * U_ + u] = __builtin_amdgcn_exp2f(SCALE2 * (acc2 + bb));
    dst[(rh * 4 + 3) * U_ + u] = __builtin_amdgcn_exp2f(SCALE2 * (acc3 + bb));
}

// ---------------------------------------------------------------------------
// Kernel 2: fused score. Block = 256 threads handles a 16t x 32s tile for one b.
// Thread (tt = tid>>4, ss = tid&15) computes outputs (tt, ss) and (tt, ss+16).
// grid = (S/32, T/16, B) = (16, 8, 4) = 512 blocks.
// score = (bV + sum(V)) - 2 * sum_u V[u] * rcp( E[s][u]*D[t][u] + 1 )
// ---------------------------------------------------------------------------
__global__ __launch_bounds__(256) void score_kernel(
    const float* __restrict__ encE, const float* __restrict__ decE,
    const float* __restrict__ V, const float* __restrict__ bV,
    float* __restrict__ out)
{
    __shared__ float se[32][132];  // enc-exp tile, padded stride (528B rows, 16B-aligned)
    __shared__ float sd[16][132];  // dec-exp tile
    __shared__ float sv[128];      // V
    __shared__ float sC;           // bV + sum(V)

    const int b  = blockIdx.z;
    const int t0 = blockIdx.y * 16;
    const int s0 = blockIdx.x * 32;
    const int tid = threadIdx.x;

    // stage enc tile: 32 rows x 128 floats = 1024 float4 -> 4/thread, coalesced
    {
        const float4* esrc = reinterpret_cast<const float4*>(encE + (b * S_ + s0) * U_);
        #pragma unroll
        for (int j = 0; j < 4; ++j) {
            int f = tid + j * 256;
            int r = f >> 5, c4 = f & 31;
            float4 v = esrc[f];
            *reinterpret_cast<float4*>(&se[r][c4 * 4]) = v;
        }
    }
    // stage dec tile: 16 rows x 128 floats = 512 float4 -> 2/thread
    {
        const float4* dsrc = reinterpret_cast<const float4*>(decE + (b * T_ + t0) * U_);
        #pragma unroll
        for (int j = 0; j < 2; ++j) {
            int f = tid + j * 256;
            int r = f >> 5, c4 = f & 31;
            float4 v = dsrc[f];
            *reinterpret_cast<float4*>(&sd[r][c4 * 4]) = v;
        }
    }
    // stage V (32 float4) + reduce sum(V) within lanes 0..31 of wave 0
    if (tid < 32) {
        float4 v = reinterpret_cast<const float4*>(V)[tid];
        *reinterpret_cast<float4*>(&sv[tid * 4]) = v;
        float p = v.x + v.y + v.z + v.w;
        p += __shfl_xor(p, 1);
        p += __shfl_xor(p, 2);
        p += __shfl_xor(p, 4);
        p += __shfl_xor(p, 8);
        p += __shfl_xor(p, 16);
        if (tid == 0) sC = p + bV[0];
    }
    __syncthreads();

    const int tt = tid >> 4;
    const int ss = tid & 15;
    const float* dp = &sd[tt][0];
    const float* ea = &se[ss][0];
    const float* eb = &se[ss + 16][0];

    // 2-way split accumulators: halves the serial FMA dependency chain.
    float accA0 = 0.f, accA1 = 0.f, accB0 = 0.f, accB1 = 0.f;
    #pragma unroll 4
    for (int k4 = 0; k4 < 32; ++k4) {
        float4 d  = *reinterpret_cast<const float4*>(dp + k4 * 4);
        float4 a  = *reinterpret_cast<const float4*>(ea + k4 * 4);
        float4 e2 = *reinterpret_cast<const float4*>(eb + k4 * 4);
        float4 vv = *reinterpret_cast<const float4*>(&sv[k4 * 4]);
        // r = 1/(E*D+1); tanh = 1-2r folded into epilogue via sC
        accA0 += vv.x * __builtin_amdgcn_rcpf(__builtin_fmaf(a.x,  d.x, 1.f));
        accA1 += vv.y * __builtin_amdgcn_rcpf(__builtin_fmaf(a.y,  d.y, 1.f));
        accA0 += vv.z * __builtin_amdgcn_rcpf(__builtin_fmaf(a.z,  d.z, 1.f));
        accA1 += vv.w * __builtin_amdgcn_rcpf(__builtin_fmaf(a.w,  d.w, 1.f));
        accB0 += vv.x * __builtin_amdgcn_rcpf(__builtin_fmaf(e2.x, d.x, 1.f));
        accB1 += vv.y * __builtin_amdgcn_rcpf(__builtin_fmaf(e2.y, d.y, 1.f));
        accB0 += vv.z * __builtin_amdgcn_rcpf(__builtin_fmaf(e2.z, d.z, 1.f));
        accB1 += vv.w * __builtin_amdgcn_rcpf(__builtin_fmaf(e2.w, d.w, 1.f));
    }

    const float C = sC;
    const int obase = (b * T_ + t0 + tt) * S_ + s0 + ss;
    out[obase]      = C - 2.f * (accA0 + accA1);
    out[obase + 16] = C - 2.f * (accB0 + accB1);
}

// ---------------------------------------------------------------------------
extern "C" void kernel_launch(void* const* d_in, const int* in_sizes, int n_in,
                              void* d_out, int out_size, void* d_ws, size_t ws_size,
                              hipStream_t stream)
{
    const float* query = (const float*)d_in[0];
    const float* keys  = (const float*)d_in[1];
    const float* W1    = (const float*)d_in[2];
    const float* b1    = (const float*)d_in[3];
    const float* W2    = (const float*)d_in[4];
    const float* b2    = (const float*)d_in[5];
    const float* V     = (const float*)d_in[6];
    const float* bV    = (const float*)d_in[7];
    float* out = (float*)d_out;

    float* encE = (float*)d_ws;                    // [B*S][U] = 2048*128 floats (1 MB)
    float* decE = encE + (B_ * S_ * U_);           // [B*T][U] = 512*128 floats (256 KB)

    precompute_kernel<<<dim3(320), dim3(256), 0, stream>>>(
        query, keys, W1, b1, W2, b2, encE, decE);

    score_kernel<<<dim3(S_ / 32, T_ / 16, B_), dim3(256), 0, stream>>>(
        encE, decE, V, bV, out);
}

// Round 10
// 77.919 us; speedup vs baseline: 1.0607x; 1.0083x over previous
//
#include <hip/hip_runtime.h>

// Bahdanau additive attention scores:
//   enc = keys @ W1 + b1          [B,S,U]
//   dec = query @ W2 + b2         [B,T,U]
//   score[b,t,s] = bV + sum_u tanh(enc[b,s,u] + dec[b,t,u]) * V[u]
//
// B=4, T=128, S=512, D=128, U=128. All fp32.
//
// R6 (resubmit x4; broker timeouts): LDS addressing hygiene. R5 read LDS
//     tiles through generic float* pointers hoisted out of the loop; if
//     addrspace(3) inference fails those become flat_load (2x slower than
//     ds_read_b128 — the exact 2x my R4->R5 delta analysis implies). This
//     round indexes the __shared__ arrays DIRECTLY in the loop so the
//     compiler must emit ds_read_b128 with folded offset immediates.
//     Math identical to R5: tanh(x) = 1 - 2/(exp2(d)*exp2(e)+1),
//     exp factored into K1.

#define B_ 4
#define T_ 128
#define S_ 512
#define D_ 128
#define U_ 128

// 2/ln(2)
#define SCALE2 2.88539008177792681f

// ---------------------------------------------------------------------------
// Kernel 1: encE[r][u] = exp2( SCALE2*(sum_k x[r][k]*W[k][u] + bias[u]) )
// 2048 enc rows (keys) + 512 dec rows (query) = 2560 rows.
// Block = 256 threads handles 8 rows x 128 u; each thread: 4 rows, 1 u.
// blocks 0..255 -> enc (keys/W1/b1), blocks 256..319 -> dec (query/W2/b2).
// ---------------------------------------------------------------------------
__global__ __launch_bounds__(256) void precompute_kernel(
    const float* __restrict__ query, const float* __restrict__ keys,
    const float* __restrict__ W1, const float* __restrict__ b1,
    const float* __restrict__ W2, const float* __restrict__ b2,
    float* __restrict__ encE, float* __restrict__ decE)
{
    __shared__ float xs[8][132];   // 8 rows x 128 k, padded stride

    const int blk = blockIdx.x;
    const float* src;
    const float* W;
    const float* bias;
    float* dst;
    if (blk < 256) {
        int row0 = blk * 8;
        src = keys + row0 * D_;
        W = W1; bias = b1;
        dst = encE + row0 * U_;
    } else {
        int row0 = (blk - 256) * 8;
        src = query + row0 * D_;
        W = W2; bias = b2;
        dst = decE + row0 * U_;
    }

    const int tid = threadIdx.x;

    // stage 8x128 floats = 256 float4, one per thread, fully coalesced
    {
        int r = tid >> 5;          // /32 float4-per-row
        int c4 = tid & 31;
        float4 v = reinterpret_cast<const float4*>(src)[tid];
        xs[r][c4 * 4 + 0] = v.x;
        xs[r][c4 * 4 + 1] = v.y;
        xs[r][c4 * 4 + 2] = v.z;
        xs[r][c4 * 4 + 3] = v.w;
    }
    __syncthreads();

    const int u = tid & 127;
    const int rh = (tid >> 7) * 4; // 0 or 4 -> rows rh..rh+3
    const float bb = bias[u];

    float acc0 = 0.f, acc1 = 0.f, acc2 = 0.f, acc3 = 0.f;
    #pragma unroll 4
    for (int k4 = 0; k4 < 32; ++k4) {
        const int k = k4 * 4;
        float w0 = W[(k + 0) * U_ + u];
        float w1 = W[(k + 1) * U_ + u];
        float w2 = W[(k + 2) * U_ + u];
        float w3 = W[(k + 3) * U_ + u];
        // direct __shared__ indexing -> ds_read, broadcast within wave
        acc0 += xs[rh + 0][k] * w0 + xs[rh + 0][k + 1] * w1 + xs[rh + 0][k + 2] * w2 + xs[rh + 0][k + 3] * w3;
        acc1 += xs[rh + 1][k] * w0 + xs[rh + 1][k + 1] * w1 + xs[rh + 1][k + 2] * w2 + xs[rh + 1][k + 3] * w3;
        acc2 += xs[rh + 2][k] * w0 + xs[rh + 2][k + 1] * w1 + xs[rh + 2][k + 2] * w2 + xs[rh + 2][k + 3] * w3;
        acc3 += xs[rh + 3][k] * w0 + xs[rh + 3][k + 1] * w1 + xs[rh + 3][k + 2] * w2 + xs[rh + 3][k + 3] * w3;
    }

    dst[(rh + 0) * U_ + u] = __builtin_amdgcn_exp2f(SCALE2 * (acc0 + bb));
    dst[(rh + 1) * U_ + u] = __builtin_amdgcn_exp2f(SCALE2 * (acc1 + bb));
    dst[(rh + 2) * U_ + u] = __builtin_amdgcn_exp2f(SCALE2 * (acc2 + bb));
    dst[(rh + 3) * U_ + u] = __builtin_amdgcn_exp2f(SCALE2 * (acc3 + bb));
}

// ---------------------------------------------------------------------------
// Kernel 2: fused score. Block = 256 threads handles a 16t x 32s tile for one b.
// Thread (tt = tid>>4, ss = tid&15) computes outputs (tt, ss) and (tt, ss+16).
// grid = (S/32, T/16, B) = (16, 8, 4) = 512 blocks.
// score = (bV + sum(V)) - 2 * sum_u V[u] * rcp( E[s][u]*D[t][u] + 1 )
// ---------------------------------------------------------------------------
__global__ __launch_bounds__(256) void score_kernel(
    const float* __restrict__ encE, const float* __restrict__ decE,
    const float* __restrict__ V, const float* __restrict__ bV,
    float* __restrict__ out)
{
    __shared__ float4 se[32][33];  // enc-exp tile as float4[32 rows][32 quads +1 pad]
    __shared__ float4 sd[16][33];  // dec-exp tile
    __shared__ float4 sv[32];      // V
    __shared__ float sC;           // bV + sum(V)

    const int b  = blockIdx.z;
    const int t0 = blockIdx.y * 16;
    const int s0 = blockIdx.x * 32;
    const int tid = threadIdx.x;

    // stage enc tile: 32 rows x 32 quads = 1024 float4 -> 4/thread, coalesced
    {
        const float4* esrc = reinterpret_cast<const float4*>(encE + (b * S_ + s0) * U_);
        #pragma unroll
        for (int j = 0; j < 4; ++j) {
            int f = tid + j * 256;
            se[f >> 5][f & 31] = esrc[f];
        }
    }
    // stage dec tile: 16 rows x 32 quads = 512 float4 -> 2/thread
    {
        const float4* dsrc = reinterpret_cast<const float4*>(decE + (b * T_ + t0) * U_);
        #pragma unroll
        for (int j = 0; j < 2; ++j) {
            int f = tid + j * 256;
            sd[f >> 5][f & 31] = dsrc[f];
        }
    }
    // stage V (32 float4) + reduce sum(V) within lanes 0..31 of wave 0
    if (tid < 32) {
        float4 v = reinterpret_cast<const float4*>(V)[tid];
        sv[tid] = v;
        float p = v.x + v.y + v.z + v.w;
        p += __shfl_xor(p, 1);
        p += __shfl_xor(p, 2);
        p += __shfl_xor(p, 4);
        p += __shfl_xor(p, 8);
        p += __shfl_xor(p, 16);
        if (tid == 0) sC = p + bV[0];
    }
    __syncthreads();

    const int tt = tid >> 4;
    const int ss = tid & 15;

    // 2-way split accumulators: halves the serial FMA dependency chain.
    float accA0 = 0.f, accA1 = 0.f, accB0 = 0.f, accB1 = 0.f;
    #pragma unroll 4
    for (int k4 = 0; k4 < 32; ++k4) {
        // direct __shared__ indexing -> guaranteed ds_read_b128
        float4 d  = sd[tt][k4];
        float4 a  = se[ss][k4];
        float4 e2 = se[ss + 16][k4];
        float4 vv = sv[k4];
        // r = 1/(E*D+1); tanh = 1-2r folded into epilogue via sC
        accA0 += vv.x * __builtin_amdgcn_rcpf(__builtin_fmaf(a.x,  d.x, 1.f));
        accA1 += vv.y * __builtin_amdgcn_rcpf(__builtin_fmaf(a.y,  d.y, 1.f));
        accA0 += vv.z * __builtin_amdgcn_rcpf(__builtin_fmaf(a.z,  d.z, 1.f));
        accA1 += vv.w * __builtin_amdgcn_rcpf(__builtin_fmaf(a.w,  d.w, 1.f));
        accB0 += vv.x * __builtin_amdgcn_rcpf(__builtin_fmaf(e2.x, d.x, 1.f));
        accB1 += vv.y * __builtin_amdgcn_rcpf(__builtin_fmaf(e2.y, d.y, 1.f));
        accB0 += vv.z * __builtin_amdgcn_rcpf(__builtin_fmaf(e2.z, d.z, 1.f));
        accB1 += vv.w * __builtin_amdgcn_rcpf(__builtin_fmaf(e2.w, d.w, 1.f));
    }

    const float C = sC;
    const int obase = (b * T_ + t0 + tt) * S_ + s0 + ss;
    out[obase]      = C - 2.f * (accA0 + accA1);
    out[obase + 16] = C - 2.f * (accB0 + accB1);
}

// ---------------------------------------------------------------------------
extern "C" void kernel_launch(void* const* d_in, const int* in_sizes, int n_in,
                              void* d_out, int out_size, void* d_ws, size_t ws_size,
                              hipStream_t stream)
{
    const float* query = (const float*)d_in[0];
    const float* keys  = (const float*)d_in[1];
    const float* W1    = (const float*)d_in[2];
    const float* b1    = (const float*)d_in[3];
    const float* W2    = (const float*)d_in[4];
    const float* b2    = (const float*)d_in[5];
    const float* V     = (const float*)d_in[6];
    const float* bV    = (const float*)d_in[7];
    float* out = (float*)d_out;

    float* encE = (float*)d_ws;                    // [B*S][U] = 2048*128 floats (1 MB)
    float* decE = encE + (B_ * S_ * U_);           // [B*T][U] = 512*128 floats (256 KB)

    precompute_kernel<<<dim3(320), dim3(256), 0, stream>>>(
        query, keys, W1, b1, W2, b2, encE, decE);

    score_kernel<<<dim3(S_ / 32, T_ / 16, B_), dim3(256), 0, stream>>>(
        encE, decE, V, bV, out);
}